// Round 8
// baseline (3713.058 us; speedup 1.0000x reference)
//
#include <hip/hip_runtime.h>
#include <stdint.h>

// MDLSTM2D: B=16, D0=D1=64, F=U=128, 5 gates (f0,f1,i,o,c)
// ROUND 8 THEORY (fits all r0-r7 evidence): the recurrence is marginally
// stable (f0+f1 ~ 1) and amplifies rounding noise ~10^3-10^4x over 127-step
// chains. fp16 P/U (5e-4) -> O(1) saturated divergence (r1/r4/r5/r6 = 1.46875
// bit-identical across 4 sync schemes; r7 different arithmetic -> 1.4296875).
// The 2% threshold exists to absorb amplified f32-level noise. FIX: f32
// everywhere. P doesn't fit ws in f32 (167.8 MB > 151.3), so each launch
// fuses: recurrence(diag d) + projection(diag d+1) into a 2-diagonal f32
// P-ring (5.2 MB). Cross-launch visibility via dispatch boundaries (r6-proven).

typedef float f32x2 __attribute__((ext_vector_type(2)));

__device__ __forceinline__ float sigm(float x) { return 1.f / (1.f + expf(-x)); }

__global__ __launch_bounds__(256) void step_kernel(
    const float* __restrict__ x,
    const float* __restrict__ w0, const float* __restrict__ w1, const float* __restrict__ w2,
    const float* __restrict__ w3, const float* __restrict__ w4,
    const float* __restrict__ u0, const float* __restrict__ u1, const float* __restrict__ u2,
    const float* __restrict__ u3, const float* __restrict__ u4,
    const float* __restrict__ bb0, const float* __restrict__ bb1, const float* __restrict__ bb2,
    const float* __restrict__ bb3, const float* __restrict__ bb4,
    float* __restrict__ Pring, float* __restrict__ hbuf, float* __restrict__ cbuf,
    float* __restrict__ out, int d, int cnt_d, int lo_d, int lo_n) {
  __shared__ float hu_l[16][132];
  __shared__ float hl_l[16][132];
  const int tid = threadIdx.x;

  if ((int)blockIdx.x < 4 * cnt_d) {
    // ---------- recurrence: one (q, cell) of diagonal d ----------
    const int q = blockIdx.x & 3;
    const int i = lo_d + (blockIdx.x >> 2);
    const int j = d - i;
    const int cell = (i << 6) + j;
    for (int idx = tid; idx < 2048; idx += 256) {
      const int b = idx >> 7, k = idx & 127;
      hu_l[b][k] = (i > 0) ? hbuf[(size_t)(cell - 64) * 2048 + b * 128 + k] : 0.f;
      hl_l[b][k] = (j > 0) ? hbuf[(size_t)(cell - 1) * 2048 + b * 128 + k] : 0.f;
    }
    __syncthreads();
    const int b = tid >> 4, pair = tid & 15;
    const int n = q * 32 + pair * 2;
    const float* Up0 = u0 + n;
    const float* Up1 = u1 + n;
    const float* Up2 = u2 + n;
    const float* Up3 = u3 + n;
    const float* Up4 = u4 + n;
    float d0a = 0, d0b = 0, d1a = 0, d1b = 0, d2a = 0, d2b = 0;
    float d3a = 0, d3b = 0, d4a = 0, d4b = 0;
#pragma unroll 4
    for (int k = 0; k < 128; ++k) {
      const float a = hu_l[b][k], l = hl_l[b][k], s = a + l;
      const f32x2 t0 = *(const f32x2*)(Up0 + k * 128);
      const f32x2 t1 = *(const f32x2*)(Up1 + k * 128);
      const f32x2 t2 = *(const f32x2*)(Up2 + k * 128);
      const f32x2 t3 = *(const f32x2*)(Up3 + k * 128);
      const f32x2 t4 = *(const f32x2*)(Up4 + k * 128);
      d0a += a * t0[0]; d0b += a * t0[1];
      d1a += l * t1[0]; d1b += l * t1[1];
      d2a += s * t2[0]; d2b += s * t2[1];
      d3a += s * t3[0]; d3b += s * t3[1];
      d4a += s * t4[0]; d4b += s * t4[1];
    }
    const float* Pc = Pring + (size_t)((d & 1) * 64 + i) * 10240 + b * 128 + n;
    const f32x2 p0 = *(const f32x2*)(Pc);
    const f32x2 p1 = *(const f32x2*)(Pc + 2048);
    const f32x2 p2 = *(const f32x2*)(Pc + 4096);
    const f32x2 p3 = *(const f32x2*)(Pc + 6144);
    const f32x2 p4 = *(const f32x2*)(Pc + 8192);
    const float f0a = sigm(p0[0] + d0a), f0b = sigm(p0[1] + d0b);
    const float f1a = sigm(p1[0] + d1a), f1b = sigm(p1[1] + d1b);
    const float ita = sigm(p2[0] + d2a), itb = sigm(p2[1] + d2b);
    const float ota = sigm(p3[0] + d3a), otb = sigm(p3[1] + d3b);
    const float cpa = tanhf(p4[0] + d4a), cpb = tanhf(p4[1] + d4b);
    f32x2 cu = {0.f, 0.f}, cl = {0.f, 0.f};
    if (i > 0) cu = *(const f32x2*)(cbuf + (size_t)(cell - 64) * 2048 + b * 128 + n);
    if (j > 0) cl = *(const f32x2*)(cbuf + (size_t)(cell - 1) * 2048 + b * 128 + n);
    const float ca = f0a * cu[0] + f1a * cl[0] + ita * cpa;
    const float cb = f0b * cu[1] + f1b * cl[1] + itb * cpb;
    const float ha = ota * tanhf(ca), hb = otb * tanhf(cb);
    *(f32x2*)(cbuf + (size_t)cell * 2048 + b * 128 + n) = (f32x2){ca, cb};
    *(f32x2*)(hbuf + (size_t)cell * 2048 + b * 128 + n) = (f32x2){ha, hb};
    *(f32x2*)(out + (((size_t)b * 64 + i) * 64 + j) * 128 + n) = (f32x2){ha, hb};
  } else {
    // ---------- projection: one (cell, b-half) of diagonal d+1 ----------
    const int pidx = blockIdx.x - 4 * cnt_d;
    const int i2 = lo_n + (pidx >> 1);
    const int j2 = (d + 1) - i2;
    const int bh = (pidx & 1) * 8;
    float(*xs)[132] = hu_l;  // reuse LDS: [8][132] fits in hu_l
    for (int idx = tid; idx < 1024; idx += 256) {
      const int bs = idx >> 7, f = idx & 127;
      xs[bs][f] = x[(((size_t)(bh + bs) * 64 + i2) * 64 + j2) * 128 + f];
    }
    __syncthreads();
    const int n = tid & 127, bs0 = (tid >> 7) * 4;
    const float* W[5] = {w0, w1, w2, w3, w4};
    const float* Bs[5] = {bb0, bb1, bb2, bb3, bb4};
    float acc[5][4];
#pragma unroll
    for (int g = 0; g < 5; ++g) {
      const float bias = Bs[g][n];
#pragma unroll
      for (int e = 0; e < 4; ++e) acc[g][e] = bias;
    }
    for (int f = 0; f < 128; ++f) {
      const float xv0 = xs[bs0][f], xv1 = xs[bs0 + 1][f];
      const float xv2 = xs[bs0 + 2][f], xv3 = xs[bs0 + 3][f];
#pragma unroll
      for (int g = 0; g < 5; ++g) {
        const float wv = W[g][f * 128 + n];
        acc[g][0] += wv * xv0; acc[g][1] += wv * xv1;
        acc[g][2] += wv * xv2; acc[g][3] += wv * xv3;
      }
    }
    const int par = (d + 1) & 1;
#pragma unroll
    for (int g = 0; g < 5; ++g)
#pragma unroll
      for (int e = 0; e < 4; ++e)
        Pring[((size_t)(par * 64 + i2) * 5 + g) * 2048 + (bh + bs0 + e) * 128 + n] = acc[g][e];
  }
}

extern "C" void kernel_launch(void* const* d_in, const int* in_sizes, int n_in,
                              void* d_out, int out_size, void* d_ws, size_t ws_size,
                              hipStream_t stream) {
  const float* x = (const float*)d_in[0];
  const float* w0 = (const float*)d_in[1];
  const float* u0 = (const float*)d_in[2];
  const float* b0 = (const float*)d_in[3];
  const float* w1 = (const float*)d_in[4];
  const float* u1 = (const float*)d_in[5];
  const float* b1 = (const float*)d_in[6];
  const float* w2 = (const float*)d_in[7];
  const float* u2 = (const float*)d_in[8];
  const float* b2 = (const float*)d_in[9];
  const float* w3 = (const float*)d_in[10];
  const float* u3 = (const float*)d_in[11];
  const float* b3 = (const float*)d_in[12];
  const float* w4 = (const float*)d_in[13];
  const float* u4 = (const float*)d_in[14];
  const float* b4 = (const float*)d_in[15];

  char* ws = (char*)d_ws;
  // layout: Pring[2][64][5][16][128] f32 = 5,242,880 ; hbuf 33,554,432 ; cbuf 33,554,432
  const size_t OFF_PR = 0;
  const size_t OFF_H = 5242880;
  const size_t OFF_C = OFF_H + (size_t)4096 * 2048 * 4;     // 38,797,312
  const size_t OFF_END = OFF_C + (size_t)4096 * 2048 * 4;   // 72,351,744
  if (ws_size < OFF_END) return;

  float* Pring = (float*)(ws + OFF_PR);
  float* hbuf = (float*)(ws + OFF_H);
  float* cbuf = (float*)(ws + OFF_C);
  float* out = (float*)d_out;

  // init: projection-only launch for diagonal 0
  step_kernel<<<2, 256, 0, stream>>>(x, w0, w1, w2, w3, w4, u0, u1, u2, u3, u4,
                                     b0, b1, b2, b3, b4, Pring, hbuf, cbuf, out,
                                     -1, 0, 0, 0);
  for (int d = 0; d <= 126; ++d) {
    const int lo_d = d > 63 ? d - 63 : 0;
    const int hi_d = d < 63 ? d : 63;
    const int cnt_d = hi_d - lo_d + 1;
    const int dn = d + 1;
    const int lo_n = dn > 63 ? dn - 63 : 0;
    const int hi_n = dn < 63 ? dn : 63;
    const int cnt_n = dn <= 126 ? (hi_n - lo_n + 1) : 0;
    const int grid = 4 * cnt_d + 2 * cnt_n;
    step_kernel<<<grid, 256, 0, stream>>>(x, w0, w1, w2, w3, w4, u0, u1, u2, u3, u4,
                                          b0, b1, b2, b3, b4, Pring, hbuf, cbuf, out,
                                          d, cnt_d, lo_d, lo_n);
  }
}